// Round 6
// baseline (475.689 us; speedup 1.0000x reference)
//
#include <hip/hip_runtime.h>
#include <hip/hip_bf16.h>

#define E_CNT 160000
#define N_CNT 10000

#define INV_STEP   2.125f          /* 17/8 */
#define EMB_C      33.734292f      /* 1.14136 * e^2 * sqrt(16) */
#define INVS320    0.05590170f     /* 1/sqrt(320) */
#define INVS8      0.35355339f     /* 1/sqrt(8)   */
#define INV_SQRT3  0.57735027f
#define KSCALE     0.051031036f    /* 0.25 (w/sqrt16) * 1/sqrt(24) (fctp norm) */

/* ---- workspace layout (float-sized offsets) ---- */
#define OFF_FLAG   0          /* 16 floats reserved (int flag at [0]) */
#define OFF_XF     16         /* 400000 */
#define OFF_EAF    400016     /* 640000 */
#define OFF_AMFF   1040016    /* 160000 */
#define OFF_WQ0F   1200016    /* 256 */
#define OFF_WQ1F   1200272    /* 64  */
#define OFF_WD0F   1200336    /* 256 */
#define OFF_WD1F   1200592    /* 64  */
#define OFF_WK1F   1200656    /* 256 */
#define OFF_WV1F   1200912    /* 256 */
#define OFF_WK2F   1201168    /* 9216 */
#define OFF_WV2F   1210384    /* 9216 */
#define OFF_P      1219600    /* 400000 */
#define OFF_EXPV   1619600    /* 160000 */
#define OFF_VBUF   1779600    /* 6400000 */
#define OFF_DEG    8179600    /* 10000 ints  (dst) */
#define OFF_START  8189600    /* 10001 ints */
#define OFF_CURS   8199616    /* 10000 ints -- reused as Z after fill is done */
#define OFF_Z      8199616    /* alias of OFF_CURS (dead after fill; zeroed in nodePG) */
#define OFF_ELIST  8209616    /* 160000 ints */
#define OFF_DEG2   8369616    /* 10000 ints  (src) */
#define OFF_START2 8379616    /* 10001 ints */
#define OFF_CURS2  8389632    /* 10000 ints */
#define OFF_ELIST2 8399632    /* 160000 ints */
#define OFF_G      8559632    /* 30,720,000 bf16 = 15,360,000 float slots */
/* total 23,919,632 floats = 95.7 MB (same extent as R5 -- verified mapped) */

static __device__ __forceinline__ float bf2f(__hip_bfloat16 b) { return __bfloat162float(b); }
static __device__ __forceinline__ float sanitize(float v) {
    return fminf(fmaxf(v, -1e30f), 1e30f);
}
static __device__ __forceinline__ unsigned short f2bf(float f) {
    unsigned x = __float_as_uint(f);
    unsigned r = (x + 0x7fffu + ((x >> 16) & 1u)) >> 16;   /* RN-even */
    return (unsigned short)r;
}
static __device__ __forceinline__ float bflo(unsigned u) { return __uint_as_float(u << 16); }
static __device__ __forceinline__ float bfhi(unsigned u) { return __uint_as_float(u & 0xffff0000u); }

// ---------------- prep: inline dtype detect + ingest + zero deg arrays ----------------
__global__ __launch_bounds__(256) void prep_kernel(
    const void* __restrict__ x,   const void* __restrict__ ea,  const void* __restrict__ amf,
    const void* __restrict__ Wq0, const void* __restrict__ Wq1,
    const void* __restrict__ Wk1, const void* __restrict__ Wk2,
    const void* __restrict__ Wv1, const void* __restrict__ Wv2,
    const void* __restrict__ Wd0, const void* __restrict__ Wd1,
    float* __restrict__ ws)
{
    __shared__ int sflag;
    const int tid = threadIdx.x;
    if (tid == 0) {
        const unsigned short* xb = (const unsigned short*)x;
        int cnt = 0;
        for (int k = 0; k < 256; k += 2) {          /* even u16 = fp32 low mantissa halves */
            unsigned e = (unsigned)((xb[k] >> 7) & 0xFF);
            if (e >= 141) ++cnt;
        }
        sflag = (cnt >= 8) ? 1 : 0;                  /* 1 = inputs are fp32 */
        if (blockIdx.x == 0) *(int*)ws = sflag;      /* for gather's output dtype */
    }
    __syncthreads();
    const int f32 = sflag;
    const int i = blockIdx.x * 256 + tid;
#define CV(p, idx) (f32 ? ((const float*)(p))[idx] : bf2f(((const __hip_bfloat16*)(p))[idx]))
    if (i < 400000) ws[OFF_XF + i]   = CV(x, i);
    if (i < 640000) ws[OFF_EAF + i]  = CV(ea, i);
    if (i < 160000) ws[OFF_AMFF + i] = CV(amf, i);
    if (i < 9216) { ws[OFF_WK2F + i] = CV(Wk2, i); ws[OFF_WV2F + i] = CV(Wv2, i); }
    if (i < 256) {
        ws[OFF_WQ0F + i] = CV(Wq0, i); ws[OFF_WD0F + i] = CV(Wd0, i);
        ws[OFF_WK1F + i] = CV(Wk1, i); ws[OFF_WV1F + i] = CV(Wv1, i);
    }
    if (i < 64) { ws[OFF_WQ1F + i] = CV(Wq1, i); ws[OFF_WD1F + i] = CV(Wd1, i); }
    if (i < 10000) { ((int*)(ws + OFF_DEG))[i] = 0; ((int*)(ws + OFF_DEG2))[i] = 0; }
#undef CV
}

// ---------------- CSR build: both src and dst in one pass each ----------------
__global__ __launch_bounds__(256) void count_kernel(const int* __restrict__ ei, float* __restrict__ ws)
{
    const int e = blockIdx.x * 256 + threadIdx.x;
    if (e >= E_CNT) return;
    atomicAdd((int*)(ws + OFF_DEG)  + ei[E_CNT + e], 1);   /* dst */
    atomicAdd((int*)(ws + OFF_DEG2) + ei[e], 1);           /* src */
}

__global__ __launch_bounds__(512) void scan_kernel(float* __restrict__ ws)
{
    __shared__ int ssum[512];
    const int t    = threadIdx.x;
    const int half = t >> 8;          /* 0 = dst CSR, 1 = src CSR */
    const int lt   = t & 255;
    int* deg   = (int*)(ws + (half ? OFF_DEG2   : OFF_DEG));
    int* start = (int*)(ws + (half ? OFF_START2 : OFF_START));
    int* curs  = (int*)(ws + (half ? OFF_CURS2  : OFF_CURS));
    const int base = lt * 40;
    int s = 0;
    for (int k = 0; k < 40; ++k) {
        int idx = base + k;
        if (idx < N_CNT) s += deg[idx];
    }
    ssum[t] = s;
    __syncthreads();
    for (int off = 1; off < 256; off <<= 1) {
        int v = (lt >= off) ? ssum[t - off] : 0;
        __syncthreads();
        ssum[t] += v;
        __syncthreads();
    }
    int run = ssum[t] - s;
    for (int k = 0; k < 40; ++k) {
        int idx = base + k;
        if (idx < N_CNT) {
            start[idx] = run;
            curs[idx]  = run;
            run += deg[idx];
        }
    }
    if (lt == 255) start[N_CNT] = E_CNT;
}

__global__ __launch_bounds__(256) void fill_kernel(const int* __restrict__ ei, float* __restrict__ ws)
{
    const int e = blockIdx.x * 256 + threadIdx.x;
    if (e >= E_CNT) return;
    int pd = atomicAdd((int*)(ws + OFF_CURS)  + ei[E_CNT + e], 1);
    ((int*)(ws + OFF_ELIST))[pd] = e;
    int ps = atomicAdd((int*)(ws + OFF_CURS2) + ei[e], 1);
    ((int*)(ws + OFF_ELIST2))[ps] = e;
}

// ---------------- fused node kernel: blocks [0,1250) build G, [1250,1290) build P + zero z ----------------
// G row layout per (n,p,c): 96 bf16 = 48 u32 = 12 uint4:
// [0..15] G1[w], [16..23] G2[w], [24+w*3+i] G3[w][i] (w<8), [48+w*3+i] G4[w][i] (1/sqrt3 folded)
__global__ __launch_bounds__(256) void nodepg_kernel(float* __restrict__ ws)
{
    const int tid = threadIdx.x;
    if (blockIdx.x >= 1250) {
        /* ---- P part + z zeroing (z aliases dst-CURS, dead after fill) ---- */
        const int n = (blockIdx.x - 1250) * 256 + tid;
        if (n >= N_CNT) return;
        ws[OFF_Z + n] = 0.f;
        const float* WQ0 = ws + OFF_WQ0F;
        const float* WQ1 = ws + OFF_WQ1F;
        const float* WD0 = ws + OFF_WD0F;
        const float* WD1 = ws + OFF_WD1F;
        float xs[40];
        const float4* xr = (const float4*)(ws + OFF_XF + n * 40);
#pragma unroll
        for (int k = 0; k < 10; ++k) {
            float4 f = xr[k];
            xs[4 * k + 0] = f.x; xs[4 * k + 1] = f.y; xs[4 * k + 2] = f.z; xs[4 * k + 3] = f.w;
        }
        float q0[16];
#pragma unroll
        for (int w = 0; w < 16; ++w) {
            float s = 0.f;
#pragma unroll
            for (int u = 0; u < 16; ++u) s = fmaf(xs[u], WQ0[u * 16 + w], s);
            q0[w] = s * 0.25f;
        }
        float* pn = ws + OFF_P + n * 40;
#pragma unroll
        for (int v = 0; v < 16; ++v) {
            float s = 0.f;
#pragma unroll
            for (int w = 0; w < 16; ++w) s = fmaf(q0[w], WD0[w * 16 + v], s);
            pn[v] = sanitize(s * INVS320);
        }
        float q1[24];
#pragma unroll
        for (int w = 0; w < 8; ++w) {
            float s0 = 0.f, s1 = 0.f, s2 = 0.f;
#pragma unroll
            for (int u = 0; u < 8; ++u) {
                float wq = WQ1[u * 8 + w];
                s0 = fmaf(xs[16 + u * 3 + 0], wq, s0);
                s1 = fmaf(xs[16 + u * 3 + 1], wq, s1);
                s2 = fmaf(xs[16 + u * 3 + 2], wq, s2);
            }
            q1[w * 3 + 0] = s0 * INVS8;
            q1[w * 3 + 1] = s1 * INVS8;
            q1[w * 3 + 2] = s2 * INVS8;
        }
#pragma unroll
        for (int v = 0; v < 8; ++v) {
            float s0 = 0.f, s1 = 0.f, s2 = 0.f;
#pragma unroll
            for (int w = 0; w < 8; ++w) {
                float wd = WD1[w * 8 + v];
                s0 = fmaf(q1[w * 3 + 0], wd, s0);
                s1 = fmaf(q1[w * 3 + 1], wd, s1);
                s2 = fmaf(q1[w * 3 + 2], wd, s2);
            }
            const float sc = INVS320 * INV_SQRT3;
            pn[16 + v * 3 + 0] = sanitize(s0 * sc);
            pn[16 + v * 3 + 1] = sanitize(s1 * sc);
            pn[16 + v * 3 + 2] = sanitize(s2 * sc);
        }
        return;
    }
    /* ---- G part: thread = (pass, c, node) ---- */
    const int t = blockIdx.x * 256 + tid;              /* < 320000 */
    const int p   = t / 160000;
    const int rem = t - p * 160000;
    const int c   = rem / 10000;
    const int n   = rem - c * 10000;

    const float* W2 = ws + (p ? OFF_WV2F : OFF_WK2F) + c * 576;
    const float* xv = ws + OFF_XF + n * 40;
    float x0[16], x1[24];
#pragma unroll
    for (int u = 0; u < 16; ++u) x0[u] = xv[u];
#pragma unroll
    for (int u = 0; u < 24; ++u) x1[u] = xv[16 + u];

    float out[96];
#pragma unroll
    for (int w = 0; w < 16; ++w) {
        float s = 0.f;
#pragma unroll
        for (int u = 0; u < 16; ++u) s = fmaf(W2[u * 16 + w], x0[u], s);
        out[w] = s;
    }
#pragma unroll
    for (int w = 0; w < 8; ++w) {
        float s = 0.f;
#pragma unroll
        for (int u = 0; u < 16; ++u) s = fmaf(W2[256 + u * 8 + w], x0[u], s);
        out[16 + w] = s;
    }
#pragma unroll
    for (int w = 0; w < 8; ++w) {
        float s0 = 0.f, s1 = 0.f, s2 = 0.f;
#pragma unroll
        for (int u = 0; u < 8; ++u) {
            float wv = W2[384 + u * 8 + w];
            s0 = fmaf(wv, x1[u * 3 + 0], s0);
            s1 = fmaf(wv, x1[u * 3 + 1], s1);
            s2 = fmaf(wv, x1[u * 3 + 2], s2);
        }
        out[24 + w * 3 + 0] = s0;
        out[24 + w * 3 + 1] = s1;
        out[24 + w * 3 + 2] = s2;
    }
#pragma unroll
    for (int w = 0; w < 16; ++w) {
        float s0 = 0.f, s1 = 0.f, s2 = 0.f;
#pragma unroll
        for (int u = 0; u < 8; ++u) {
            float wv = W2[448 + u * 16 + w];
            s0 = fmaf(wv, x1[u * 3 + 0], s0);
            s1 = fmaf(wv, x1[u * 3 + 1], s1);
            s2 = fmaf(wv, x1[u * 3 + 2], s2);
        }
        out[48 + w * 3 + 0] = s0 * INV_SQRT3;
        out[48 + w * 3 + 1] = s1 * INV_SQRT3;
        out[48 + w * 3 + 2] = s2 * INV_SQRT3;
    }

    uint4 ov[12];
    unsigned* ou = (unsigned*)ov;
#pragma unroll
    for (int k = 0; k < 48; ++k)
        ou[k] = (unsigned)f2bf(out[2 * k]) | ((unsigned)f2bf(out[2 * k + 1]) << 16);
    uint4* dp = (uint4*)((unsigned short*)(ws + OFF_G) + ((size_t)n * 2 + p) * 1536 + c * 96);
#pragma unroll
    for (int q = 0; q < 12; ++q) dp[q] = ov[q];
}

// ---------------- per-edge: thread = (edge, pass, c-half); pair-reduce via shfl ----------------
__global__ __launch_bounds__(256) void edge_kernel(
    const int* __restrict__ ei, float* __restrict__ ws)
{
    const int tid   = threadIdx.x;
    const int chalf = tid & 1;
    const int unit  = tid >> 1;
    const int pass  = unit & 1;
    const int el    = unit >> 1;                       /* 0..63 */
    const int sidx  = blockIdx.x * 64 + el;            /* 2500*64 = 160000 exact */
    const int e     = ((const int*)(ws + OFF_ELIST2))[sidx];
    const int src   = ei[e];
    const int dst   = ei[E_CNT + e];

    const float d   = ws[OFF_AMFF + e];
    const float dsv = d * INV_STEP;
    float emb[16];
#pragma unroll
    for (int b = 0; b < 16; ++b) {
        float t1 = dsv - (float)b;
        float t2 = (float)(b + 2) - dsv;
        float v = 0.f;
        if (t1 > 0.f && t2 > 0.f) v = EMB_C * expf(-1.f / t1 - 1.f / t2);
        emb[b] = v;
    }

    const float4 eav = ((const float4*)(ws + OFF_EAF))[e];
    const float sh0 = eav.x, s1x = eav.y, s1y = eav.z, s1z = eav.w;

    const float* W1 = ws + (pass ? OFF_WV1F : OFF_WK1F);
    const uint4* Gp = (const uint4*)((const unsigned short*)(ws + OFF_G)
                                     + ((size_t)src * 2 + pass) * 1536);

    float o0[16], o1[24], t2a[8];
#pragma unroll
    for (int i = 0; i < 16; ++i) o0[i] = 0.f;
#pragma unroll
    for (int i = 0; i < 24; ++i) o1[i] = 0.f;
#pragma unroll
    for (int i = 0; i < 8; ++i) t2a[i] = 0.f;

    const int cbase = chalf * 8;
#pragma unroll 1
    for (int ci = 0; ci < 8; ++ci) {
        const int c = cbase + ci;
        /* h_c on the fly (W1 reads: 2 distinct addrs/wave -> L1 broadcast) */
        float s = 0.f;
#pragma unroll
        for (int b = 0; b < 16; ++b) s = fmaf(emb[b], W1[b * 16 + c], s);
        s *= 0.25f;
        const float hc = s / (1.f + expf(-s));
        const float hs = hc * sh0;

        const uint4* rp = Gp + c * 12;
        unsigned ub[24];
        /* batch A: values 0..47 (G1,G2,G3) */
        {
#pragma unroll
            for (int q = 0; q < 6; ++q) {
                uint4 v = rp[q];
                ub[4 * q + 0] = v.x; ub[4 * q + 1] = v.y;
                ub[4 * q + 2] = v.z; ub[4 * q + 3] = v.w;
            }
        }
#define GVAL(k) (((k) & 1) ? bfhi(ub[(k) >> 1]) : bflo(ub[(k) >> 1]))
#pragma unroll
        for (int w = 0; w < 16; ++w) o0[w] = fmaf(hs, GVAL(w), o0[w]);
#pragma unroll
        for (int w = 0; w < 8; ++w) t2a[w] = fmaf(hc, GVAL(16 + w), t2a[w]);
#pragma unroll
        for (int w = 0; w < 8; ++w) {
            o1[w * 3 + 0] = fmaf(hs, GVAL(24 + w * 3 + 0), o1[w * 3 + 0]);
            o1[w * 3 + 1] = fmaf(hs, GVAL(24 + w * 3 + 1), o1[w * 3 + 1]);
            o1[w * 3 + 2] = fmaf(hs, GVAL(24 + w * 3 + 2), o1[w * 3 + 2]);
        }
        /* batch B: values 48..95 (G4) */
        {
#pragma unroll
            for (int q = 0; q < 6; ++q) {
                uint4 v = rp[6 + q];
                ub[4 * q + 0] = v.x; ub[4 * q + 1] = v.y;
                ub[4 * q + 2] = v.z; ub[4 * q + 3] = v.w;
            }
        }
#pragma unroll
        for (int w = 0; w < 16; ++w) {
            float g = GVAL(w * 3 + 0) * s1x;
            g = fmaf(GVAL(w * 3 + 1), s1y, g);
            g = fmaf(GVAL(w * 3 + 2), s1z, g);
            o0[w] = fmaf(hc, g, o0[w]);
        }
#undef GVAL
    }

    /* pair reduction: lanes (2k, 2k+1) hold the two c-halves of one (edge,pass) */
#pragma unroll
    for (int w = 0; w < 16; ++w) o0[w] += __shfl_xor(o0[w], 1);
#pragma unroll
    for (int w = 0; w < 24; ++w) o1[w] += __shfl_xor(o1[w], 1);
#pragma unroll
    for (int w = 0; w < 8; ++w) t2a[w] += __shfl_xor(t2a[w], 1);

    if (chalf) return;   /* even lane of each pair does the epilogue */

#pragma unroll
    for (int w = 0; w < 8; ++w) {
        o1[w * 3 + 0] = fmaf(t2a[w], s1x, o1[w * 3 + 0]);
        o1[w * 3 + 1] = fmaf(t2a[w], s1y, o1[w * 3 + 1]);
        o1[w * 3 + 2] = fmaf(t2a[w], s1z, o1[w * 3 + 2]);
    }

    if (pass == 0) {
        const float* pd = ws + OFF_P + dst * 40;
        float sc = 0.f;
#pragma unroll
        for (int j = 0; j < 16; ++j) sc = fmaf(o0[j], pd[j], sc);
#pragma unroll
        for (int j = 0; j < 24; ++j) sc = fmaf(o1[j], pd[16 + j], sc);
        sc = fminf(fmaxf(sc * KSCALE, -60.f), 60.f);
        float ct = 10.f * (1.f - d * 0.125f);
        float cutoff = (ct > 0.f) ? expf(-1.f / ct) : 0.f;
        float ev = fmaxf(cutoff * expf(sc), 0.f);
        ws[OFF_EXPV + e] = ev;
        atomicAdd(ws + OFF_Z + dst, ev);
    } else {
        float* vr = ws + OFF_VBUF + (size_t)e * 40;
#pragma unroll
        for (int j = 0; j < 16; ++j) vr[j] = sanitize(o0[j] * KSCALE);
#pragma unroll
        for (int j = 0; j < 24; ++j) vr[16 + j] = sanitize(o1[j] * KSCALE);
    }
}

// ---------------- gather: one thread per (node, feature); z precomputed ----------------
__global__ __launch_bounds__(256) void gather_kernel(
    const float* __restrict__ ws, void* __restrict__ out)
{
    const int i = blockIdx.x * 256 + threadIdx.x;
    if (i >= N_CNT * 40) return;
    const int n = i / 40;
    const int f = i - n * 40;
    const int* start = (const int*)(ws + OFF_START);
    const int* elist = (const int*)(ws + OFF_ELIST);
    const float* expv = ws + OFF_EXPV;
    const float* Vbuf = ws + OFF_VBUF;
    const int s = start[n], t = start[n + 1];

    float zz = ws[OFF_Z + n];
    const float rz = (zz > 0.f) ? 1.f / zz : 1.f;

    float acc = 0.f;
    for (int j = s; j < t; ++j) {
        const int e = elist[j];
        const float we = sqrtf(fmaxf(expv[e] * rz, 0.f));
        acc = fmaf(we, Vbuf[(size_t)e * 40 + f], acc);
    }
    acc = sanitize(acc);
    const int f32 = *(const int*)ws;
    if (f32) ((float*)out)[i] = acc;
    else     ((__hip_bfloat16*)out)[i] = __float2bfloat16(acc);
}

extern "C" void kernel_launch(void* const* d_in, const int* in_sizes, int n_in,
                              void* d_out, int out_size, void* d_ws, size_t ws_size,
                              hipStream_t stream)
{
    (void)in_sizes; (void)n_in; (void)out_size; (void)ws_size;
    const void* x   = d_in[0];
    const int*  ei  = (const int*)d_in[1];
    const void* ea  = d_in[2];
    const void* amf = d_in[5];
    const void* Wq0 = d_in[6];
    const void* Wq1 = d_in[7];
    const void* Wk1 = d_in[8];
    const void* Wk2 = d_in[9];
    const void* Wv1 = d_in[10];
    const void* Wv2 = d_in[11];
    const void* Wd0 = d_in[12];
    const void* Wd1 = d_in[13];

    float* ws = (float*)d_ws;

    prep_kernel<<<2500, 256, 0, stream>>>(x, ea, amf, Wq0, Wq1, Wk1, Wk2, Wv1, Wv2, Wd0, Wd1, ws);
    count_kernel<<<625, 256, 0, stream>>>(ei, ws);
    scan_kernel<<<1, 512, 0, stream>>>(ws);
    fill_kernel<<<625, 256, 0, stream>>>(ei, ws);
    nodepg_kernel<<<1290, 256, 0, stream>>>(ws);       /* blocks 0-1249: G; 1250-1289: P + z=0 */
    edge_kernel<<<2500, 256, 0, stream>>>(ei, ws);
    gather_kernel<<<(N_CNT * 40 + 255) / 256, 256, 0, stream>>>(ws, d_out);
}

// Round 7
// 322.515 us; speedup vs baseline: 1.4749x; 1.4749x over previous
//
#include <hip/hip_runtime.h>
#include <hip/hip_bf16.h>

#define E_CNT 160000
#define N_CNT 10000

#define INV_STEP   2.125f          /* 17/8 */
#define EMB_C      33.734292f      /* 1.14136 * e^2 * sqrt(16) */
#define INVS320    0.05590170f     /* 1/sqrt(320) */
#define INVS8      0.35355339f     /* 1/sqrt(8)   */
#define INV_SQRT3  0.57735027f
#define KSCALE     0.051031036f    /* 0.25 (w/sqrt16) * 1/sqrt(24) (fctp norm) */

/* ---- workspace layout (float-sized offsets) ---- */
#define OFF_FLAG   0          /* 16 floats reserved (int flag at [0]) */
#define OFF_XF     16         /* 400000 */
#define OFF_EAF    400016     /* 640000 */
#define OFF_AMFF   1040016    /* 160000 */
#define OFF_WQ0F   1200016    /* 256 */
#define OFF_WQ1F   1200272    /* 64  */
#define OFF_WD0F   1200336    /* 256 */
#define OFF_WD1F   1200592    /* 64  */
#define OFF_WK1F   1200656    /* 256 */
#define OFF_WV1F   1200912    /* 256 */
#define OFF_WK2F   1201168    /* 9216 */
#define OFF_WV2F   1210384    /* 9216 */
#define OFF_P      1219600    /* 400000 */
#define OFF_EXPV   1619600    /* 160000 */
#define OFF_VBUF   1779600    /* 6400000 */
#define OFF_DEG    8179600    /* 10000 ints (dst); reused as Z (zeroed at end of scan) */
#define OFF_Z      8179600    /* alias of OFF_DEG */
#define OFF_DEG2   8189600    /* 10000 ints (src) -- adjacent to DEG: single memset */
#define OFF_START  8199600    /* 10001 ints */
#define OFF_START2 8209601    /* 10001 ints */
#define OFF_CURS   8219602    /* 10000 ints */
#define OFF_CURS2  8229602    /* 10000 ints */
#define OFF_ELIST  8239602    /* 160000 ints */
#define OFF_ELIST2 8399602    /* 160000 ints */
#define OFF_G      8559632    /* 30,720,000 bf16 = 15,360,000 float slots (16B aligned) */
/* total 23,919,632 floats = 95.7 MB (same extent as R5/R6 -- verified mapped) */

static __device__ __forceinline__ float bf2f(__hip_bfloat16 b) { return __bfloat162float(b); }
static __device__ __forceinline__ float sanitize(float v) {
    return fminf(fmaxf(v, -1e30f), 1e30f);
}
static __device__ __forceinline__ unsigned short f2bf(float f) {
    unsigned x = __float_as_uint(f);
    unsigned r = (x + 0x7fffu + ((x >> 16) & 1u)) >> 16;   /* RN-even */
    return (unsigned short)r;
}
static __device__ __forceinline__ float bflo(unsigned u) { return __uint_as_float(u << 16); }
static __device__ __forceinline__ float bfhi(unsigned u) { return __uint_as_float(u & 0xffff0000u); }

// ---------------- prep: dtype detect + ingest + degree counts (DEG pre-zeroed by memset) ----------------
__global__ __launch_bounds__(256) void prep_kernel(
    const void* __restrict__ x,   const void* __restrict__ ea,  const void* __restrict__ amf,
    const void* __restrict__ Wq0, const void* __restrict__ Wq1,
    const void* __restrict__ Wk1, const void* __restrict__ Wk2,
    const void* __restrict__ Wv1, const void* __restrict__ Wv2,
    const void* __restrict__ Wd0, const void* __restrict__ Wd1,
    const int* __restrict__ ei, float* __restrict__ ws)
{
    __shared__ int sflag;
    const int tid = threadIdx.x;
    if (tid == 0) {
        const unsigned short* xb = (const unsigned short*)x;
        int cnt = 0;
        for (int k = 0; k < 256; k += 2) {
            unsigned e = (unsigned)((xb[k] >> 7) & 0xFF);
            if (e >= 141) ++cnt;
        }
        sflag = (cnt >= 8) ? 1 : 0;                  /* 1 = inputs are fp32 */
        if (blockIdx.x == 0) *(int*)ws = sflag;
    }
    __syncthreads();
    const int f32 = sflag;
    const int i = blockIdx.x * 256 + tid;
#define CV(p, idx) (f32 ? ((const float*)(p))[idx] : bf2f(((const __hip_bfloat16*)(p))[idx]))
    if (i < 400000) ws[OFF_XF + i]   = CV(x, i);
    if (i < 640000) ws[OFF_EAF + i]  = CV(ea, i);
    if (i < 160000) {
        ws[OFF_AMFF + i] = CV(amf, i);
        atomicAdd((int*)(ws + OFF_DEG)  + ei[E_CNT + i], 1);   /* dst degree */
        atomicAdd((int*)(ws + OFF_DEG2) + ei[i], 1);           /* src degree */
    }
    if (i < 9216) { ws[OFF_WK2F + i] = CV(Wk2, i); ws[OFF_WV2F + i] = CV(Wv2, i); }
    if (i < 256) {
        ws[OFF_WQ0F + i] = CV(Wq0, i); ws[OFF_WD0F + i] = CV(Wd0, i);
        ws[OFF_WK1F + i] = CV(Wk1, i); ws[OFF_WV1F + i] = CV(Wv1, i);
    }
    if (i < 64) { ws[OFF_WQ1F + i] = CV(Wq1, i); ws[OFF_WD1F + i] = CV(Wd1, i); }
#undef CV
}

// ---------------- dual scan (512 threads: half dst, half src) + zero Z at end ----------------
__global__ __launch_bounds__(512) void scan_kernel(float* __restrict__ ws)
{
    __shared__ int ssum[512];
    const int t    = threadIdx.x;
    const int half = t >> 8;
    const int lt   = t & 255;
    int* deg   = (int*)(ws + (half ? OFF_DEG2   : OFF_DEG));
    int* start = (int*)(ws + (half ? OFF_START2 : OFF_START));
    int* curs  = (int*)(ws + (half ? OFF_CURS2  : OFF_CURS));
    const int base = lt * 40;
    int s = 0;
    for (int k = 0; k < 40; ++k) {
        int idx = base + k;
        if (idx < N_CNT) s += deg[idx];
    }
    ssum[t] = s;
    __syncthreads();
    for (int off = 1; off < 256; off <<= 1) {
        int v = (lt >= off) ? ssum[t - off] : 0;
        __syncthreads();
        ssum[t] += v;
        __syncthreads();
    }
    int run = ssum[t] - s;
    for (int k = 0; k < 40; ++k) {
        int idx = base + k;
        if (idx < N_CNT) {
            start[idx] = run;
            curs[idx]  = run;
            run += deg[idx];
        }
    }
    if (lt == 255) start[N_CNT] = E_CNT;
    __syncthreads();                                   /* all deg reads done */
    for (int k = t; k < N_CNT; k += 512) ws[OFF_Z + k] = 0.f;   /* Z aliases DEG */
}

// ---------------- fused: blocks [0,625) fill, [625,1875) G, [1875,1915) P ----------------
// G row layout per (n,p,c): 96 bf16 = 48 u32 = 12 uint4:
// [0..15] G1[w], [16..23] G2[w], [24+w*3+i] G3[w][i] (w<8), [48+w*3+i] G4[w][i] (1/sqrt3 folded)
__global__ __launch_bounds__(256) void fillgp_kernel(const int* __restrict__ ei, float* __restrict__ ws)
{
    const int blk = blockIdx.x;
    const int tid = threadIdx.x;
    if (blk < 625) {
        /* ---- fill both CSRs ---- */
        const int e = blk * 256 + tid;                 /* 625*256 = 160000 exact */
        int pd = atomicAdd((int*)(ws + OFF_CURS)  + ei[E_CNT + e], 1);
        ((int*)(ws + OFF_ELIST))[pd] = e;
        int ps = atomicAdd((int*)(ws + OFF_CURS2) + ei[e], 1);
        ((int*)(ws + OFF_ELIST2))[ps] = e;
        return;
    }
    if (blk >= 1875) {
        /* ---- P part ---- */
        const int n = (blk - 1875) * 256 + tid;
        if (n >= N_CNT) return;
        const float* WQ0 = ws + OFF_WQ0F;
        const float* WQ1 = ws + OFF_WQ1F;
        const float* WD0 = ws + OFF_WD0F;
        const float* WD1 = ws + OFF_WD1F;
        float xs[40];
        const float4* xr = (const float4*)(ws + OFF_XF + n * 40);
#pragma unroll
        for (int k = 0; k < 10; ++k) {
            float4 f = xr[k];
            xs[4 * k + 0] = f.x; xs[4 * k + 1] = f.y; xs[4 * k + 2] = f.z; xs[4 * k + 3] = f.w;
        }
        float q0[16];
#pragma unroll
        for (int w = 0; w < 16; ++w) {
            float s = 0.f;
#pragma unroll
            for (int u = 0; u < 16; ++u) s = fmaf(xs[u], WQ0[u * 16 + w], s);
            q0[w] = s * 0.25f;
        }
        float* pn = ws + OFF_P + n * 40;
#pragma unroll
        for (int v = 0; v < 16; ++v) {
            float s = 0.f;
#pragma unroll
            for (int w = 0; w < 16; ++w) s = fmaf(q0[w], WD0[w * 16 + v], s);
            pn[v] = sanitize(s * INVS320);
        }
        float q1[24];
#pragma unroll
        for (int w = 0; w < 8; ++w) {
            float s0 = 0.f, s1 = 0.f, s2 = 0.f;
#pragma unroll
            for (int u = 0; u < 8; ++u) {
                float wq = WQ1[u * 8 + w];
                s0 = fmaf(xs[16 + u * 3 + 0], wq, s0);
                s1 = fmaf(xs[16 + u * 3 + 1], wq, s1);
                s2 = fmaf(xs[16 + u * 3 + 2], wq, s2);
            }
            q1[w * 3 + 0] = s0 * INVS8;
            q1[w * 3 + 1] = s1 * INVS8;
            q1[w * 3 + 2] = s2 * INVS8;
        }
#pragma unroll
        for (int v = 0; v < 8; ++v) {
            float s0 = 0.f, s1 = 0.f, s2 = 0.f;
#pragma unroll
            for (int w = 0; w < 8; ++w) {
                float wd = WD1[w * 8 + v];
                s0 = fmaf(q1[w * 3 + 0], wd, s0);
                s1 = fmaf(q1[w * 3 + 1], wd, s1);
                s2 = fmaf(q1[w * 3 + 2], wd, s2);
            }
            const float sc = INVS320 * INV_SQRT3;
            pn[16 + v * 3 + 0] = sanitize(s0 * sc);
            pn[16 + v * 3 + 1] = sanitize(s1 * sc);
            pn[16 + v * 3 + 2] = sanitize(s2 * sc);
        }
        return;
    }
    /* ---- G part: thread = (pass, c, node) ---- */
    const int t = (blk - 625) * 256 + tid;             /* < 320000 */
    const int p   = t / 160000;
    const int rem = t - p * 160000;
    const int c   = rem / 10000;
    const int n   = rem - c * 10000;

    const float* W2 = ws + (p ? OFF_WV2F : OFF_WK2F) + c * 576;
    const float* xv = ws + OFF_XF + n * 40;
    float x0[16], x1[24];
#pragma unroll
    for (int u = 0; u < 16; ++u) x0[u] = xv[u];
#pragma unroll
    for (int u = 0; u < 24; ++u) x1[u] = xv[16 + u];

    float out[96];
#pragma unroll
    for (int w = 0; w < 16; ++w) {
        float s = 0.f;
#pragma unroll
        for (int u = 0; u < 16; ++u) s = fmaf(W2[u * 16 + w], x0[u], s);
        out[w] = s;
    }
#pragma unroll
    for (int w = 0; w < 8; ++w) {
        float s = 0.f;
#pragma unroll
        for (int u = 0; u < 16; ++u) s = fmaf(W2[256 + u * 8 + w], x0[u], s);
        out[16 + w] = s;
    }
#pragma unroll
    for (int w = 0; w < 8; ++w) {
        float s0 = 0.f, s1 = 0.f, s2 = 0.f;
#pragma unroll
        for (int u = 0; u < 8; ++u) {
            float wv = W2[384 + u * 8 + w];
            s0 = fmaf(wv, x1[u * 3 + 0], s0);
            s1 = fmaf(wv, x1[u * 3 + 1], s1);
            s2 = fmaf(wv, x1[u * 3 + 2], s2);
        }
        out[24 + w * 3 + 0] = s0;
        out[24 + w * 3 + 1] = s1;
        out[24 + w * 3 + 2] = s2;
    }
#pragma unroll
    for (int w = 0; w < 16; ++w) {
        float s0 = 0.f, s1 = 0.f, s2 = 0.f;
#pragma unroll
        for (int u = 0; u < 8; ++u) {
            float wv = W2[448 + u * 16 + w];
            s0 = fmaf(wv, x1[u * 3 + 0], s0);
            s1 = fmaf(wv, x1[u * 3 + 1], s1);
            s2 = fmaf(wv, x1[u * 3 + 2], s2);
        }
        out[48 + w * 3 + 0] = s0 * INV_SQRT3;
        out[48 + w * 3 + 1] = s1 * INV_SQRT3;
        out[48 + w * 3 + 2] = s2 * INV_SQRT3;
    }

    uint4 ov[12];
    unsigned* ou = (unsigned*)ov;
#pragma unroll
    for (int k = 0; k < 48; ++k)
        ou[k] = (unsigned)f2bf(out[2 * k]) | ((unsigned)f2bf(out[2 * k + 1]) << 16);
    uint4* dp = (uint4*)((unsigned short*)(ws + OFF_G) + ((size_t)n * 2 + p) * 1536 + c * 96);
#pragma unroll
    for (int q = 0; q < 12; ++q) dp[q] = ov[q];
}

// ---------------- edge-kernel helpers ----------------
static __device__ __forceinline__ void load48(unsigned (&ub)[48], const uint4* __restrict__ rp)
{
#pragma unroll
    for (int q = 0; q < 12; ++q) {
        uint4 v = rp[q];
        ub[4 * q + 0] = v.x; ub[4 * q + 1] = v.y;
        ub[4 * q + 2] = v.z; ub[4 * q + 3] = v.w;
    }
}

static __device__ __forceinline__ void accum48(const unsigned (&ub)[48], float hc, float sh0,
    float s1x, float s1y, float s1z,
    float (&o0)[16], float (&o1)[24], float (&t2a)[8])
{
    const float hs = hc * sh0;
#define GVAL(k) (((k) & 1) ? bfhi(ub[(k) >> 1]) : bflo(ub[(k) >> 1]))
#pragma unroll
    for (int w = 0; w < 16; ++w) o0[w] = fmaf(hs, GVAL(w), o0[w]);
#pragma unroll
    for (int w = 0; w < 8; ++w) t2a[w] = fmaf(hc, GVAL(16 + w), t2a[w]);
#pragma unroll
    for (int w = 0; w < 8; ++w) {
        o1[w * 3 + 0] = fmaf(hs, GVAL(24 + w * 3 + 0), o1[w * 3 + 0]);
        o1[w * 3 + 1] = fmaf(hs, GVAL(24 + w * 3 + 1), o1[w * 3 + 1]);
        o1[w * 3 + 2] = fmaf(hs, GVAL(24 + w * 3 + 2), o1[w * 3 + 2]);
    }
#pragma unroll
    for (int w = 0; w < 16; ++w) {
        float g = GVAL(48 + w * 3 + 0) * s1x;
        g = fmaf(GVAL(48 + w * 3 + 1), s1y, g);
        g = fmaf(GVAL(48 + w * 3 + 2), s1z, g);
        o0[w] = fmaf(hc, g, o0[w]);
    }
#undef GVAL
}

// ---------------- per-edge main kernel: 2 threads/edge, ping-pong prefetch over c ----------------
// launch_bounds(256,2): allow up to 256 VGPR so both 48-word G buffers stay live (ILP > TLP here;
// R6 proved thread-splitting the c loop kills MLP).
__global__ __launch_bounds__(256, 2) void edge_kernel(
    const int* __restrict__ ei, float* __restrict__ ws)
{
    __shared__ float h_s[16 * 256];
    const int tid  = threadIdx.x;
    const int pass = tid >> 7;          /* waves 0-1: K, waves 2-3: V */
    const int lane = tid & 127;
    /* XCD swizzle: blockIdx%8 = XCD (heuristic); give each XCD a contiguous src range */
    const int b  = blockIdx.x;
    const int lb = (b < 1248) ? ((b & 7) * 156 + (b >> 3)) : b;
    const int sidx = lb * 128 + lane;   /* src-sorted edge index */
    const int e    = ((const int*)(ws + OFF_ELIST2))[sidx];
    const int src  = ei[e];
    const int dst  = ei[E_CNT + e];

    const float d   = ws[OFF_AMFF + e];
    const float dsv = d * INV_STEP;
    float emb[16];
#pragma unroll
    for (int bb = 0; bb < 16; ++bb) {
        float t1 = dsv - (float)bb;
        float t2 = (float)(bb + 2) - dsv;
        float v = 0.f;
        if (t1 > 0.f && t2 > 0.f) v = EMB_C * expf(-1.f / t1 - 1.f / t2);
        emb[bb] = v;
    }

    const float* W1 = ws + (pass ? OFF_WV1F : OFF_WK1F);
#pragma unroll 1
    for (int j = 0; j < 16; ++j) {
        float s = 0.f;
#pragma unroll
        for (int bb = 0; bb < 16; ++bb) s = fmaf(emb[bb], W1[bb * 16 + j], s);
        s *= 0.25f;
        h_s[j * 256 + tid] = s / (1.f + expf(-s));
    }

    const float4 eav = ((const float4*)(ws + OFF_EAF))[e];
    const float sh0 = eav.x, s1x = eav.y, s1y = eav.z, s1z = eav.w;

    float o0[16], o1[24], t2a[8];
#pragma unroll
    for (int i = 0; i < 16; ++i) o0[i] = 0.f;
#pragma unroll
    for (int i = 0; i < 24; ++i) o1[i] = 0.f;
#pragma unroll
    for (int i = 0; i < 8; ++i) t2a[i] = 0.f;

    const uint4* Gp = (const uint4*)((const unsigned short*)(ws + OFF_G)
                                     + ((size_t)src * 2 + pass) * 1536);

    unsigned A[48], B[48];
    load48(A, Gp);                                     /* c = 0 */
#pragma unroll 1
    for (int c = 0; c < 16; c += 2) {
        load48(B, Gp + (c + 1) * 12);                  /* prefetch c+1 */
        accum48(A, h_s[c * 256 + tid], sh0, s1x, s1y, s1z, o0, o1, t2a);
        if (c + 2 < 16) load48(A, Gp + (c + 2) * 12);  /* prefetch c+2 */
        accum48(B, h_s[(c + 1) * 256 + tid], sh0, s1x, s1y, s1z, o0, o1, t2a);
    }

#pragma unroll
    for (int w = 0; w < 8; ++w) {
        o1[w * 3 + 0] = fmaf(t2a[w], s1x, o1[w * 3 + 0]);
        o1[w * 3 + 1] = fmaf(t2a[w], s1y, o1[w * 3 + 1]);
        o1[w * 3 + 2] = fmaf(t2a[w], s1z, o1[w * 3 + 2]);
    }

    if (pass == 0) {
        const float* pd = ws + OFF_P + dst * 40;
        float sc = 0.f;
#pragma unroll
        for (int j = 0; j < 16; ++j) sc = fmaf(o0[j], pd[j], sc);
#pragma unroll
        for (int j = 0; j < 24; ++j) sc = fmaf(o1[j], pd[16 + j], sc);
        sc = fminf(fmaxf(sc * KSCALE, -60.f), 60.f);
        float ct = 10.f * (1.f - d * 0.125f);
        float cutoff = (ct > 0.f) ? expf(-1.f / ct) : 0.f;
        float ev = fmaxf(cutoff * expf(sc), 0.f);
        ws[OFF_EXPV + e] = ev;
        atomicAdd(ws + OFF_Z + dst, ev);
    } else {
        float* vr = ws + OFF_VBUF + (size_t)e * 40;
#pragma unroll
        for (int j = 0; j < 16; ++j) vr[j] = sanitize(o0[j] * KSCALE);
#pragma unroll
        for (int j = 0; j < 24; ++j) vr[16 + j] = sanitize(o1[j] * KSCALE);
    }
}

// ---------------- gather: one thread per (node, feature); z precomputed ----------------
__global__ __launch_bounds__(256) void gather_kernel(
    const float* __restrict__ ws, void* __restrict__ out)
{
    const int i = blockIdx.x * 256 + threadIdx.x;
    if (i >= N_CNT * 40) return;
    const int n = i / 40;
    const int f = i - n * 40;
    const int* start = (const int*)(ws + OFF_START);
    const int* elist = (const int*)(ws + OFF_ELIST);
    const float* expv = ws + OFF_EXPV;
    const float* Vbuf = ws + OFF_VBUF;
    const int s = start[n], t = start[n + 1];

    float zz = ws[OFF_Z + n];
    const float rz = (zz > 0.f) ? 1.f / zz : 1.f;

    float acc = 0.f;
    for (int j = s; j < t; ++j) {
        const int e = elist[j];
        const float we = sqrtf(fmaxf(expv[e] * rz, 0.f));
        acc = fmaf(we, Vbuf[(size_t)e * 40 + f], acc);
    }
    acc = sanitize(acc);
    const int f32 = *(const int*)ws;
    if (f32) ((float*)out)[i] = acc;
    else     ((__hip_bfloat16*)out)[i] = __float2bfloat16(acc);
}

extern "C" void kernel_launch(void* const* d_in, const int* in_sizes, int n_in,
                              void* d_out, int out_size, void* d_ws, size_t ws_size,
                              hipStream_t stream)
{
    (void)in_sizes; (void)n_in; (void)out_size; (void)ws_size;
    const void* x   = d_in[0];
    const int*  ei  = (const int*)d_in[1];
    const void* ea  = d_in[2];
    const void* amf = d_in[5];
    const void* Wq0 = d_in[6];
    const void* Wq1 = d_in[7];
    const void* Wk1 = d_in[8];
    const void* Wk2 = d_in[9];
    const void* Wv1 = d_in[10];
    const void* Wv2 = d_in[11];
    const void* Wd0 = d_in[12];
    const void* Wd1 = d_in[13];

    float* ws = (float*)d_ws;

    hipMemsetAsync(ws + OFF_DEG, 0, 20000 * sizeof(int), stream);   /* DEG + DEG2 adjacent */
    prep_kernel<<<2500, 256, 0, stream>>>(x, ea, amf, Wq0, Wq1, Wk1, Wk2, Wv1, Wv2, Wd0, Wd1, ei, ws);
    scan_kernel<<<1, 512, 0, stream>>>(ws);
    fillgp_kernel<<<1915, 256, 0, stream>>>(ei, ws);   /* 0-624 fill, 625-1874 G, 1875-1914 P */
    edge_kernel<<<1250, 256, 0, stream>>>(ei, ws);
    gather_kernel<<<(N_CNT * 40 + 255) / 256, 256, 0, stream>>>(ws, d_out);
}

// Round 8
// 310.091 us; speedup vs baseline: 1.5340x; 1.0401x over previous
//
#include <hip/hip_runtime.h>
#include <hip/hip_bf16.h>

#define E_CNT 160000
#define N_CNT 10000

#define INV_STEP   2.125f          /* 17/8 */
#define EMB_C      33.734292f      /* 1.14136 * e^2 * sqrt(16) */
#define INVS320    0.05590170f     /* 1/sqrt(320) */
#define INVS8      0.35355339f     /* 1/sqrt(8)   */
#define INV_SQRT3  0.57735027f
#define KSCALE     0.051031036f    /* 0.25 (w/sqrt16) * 1/sqrt(24) (fctp norm) */

/* ---- workspace layout (float-sized offsets) ---- */
#define OFF_FLAG   0          /* 16 floats reserved (int flag at [0]) */
#define OFF_XF     16         /* 400000 */
#define OFF_EAF    400016     /* 640000 */
#define OFF_AMFF   1040016    /* 160000 */
#define OFF_WQ0F   1200016    /* 256 */
#define OFF_WQ1F   1200272    /* 64  */
#define OFF_WD0F   1200336    /* 256 */
#define OFF_WD1F   1200592    /* 64  */
#define OFF_WK1F   1200656    /* 256 */
#define OFF_WV1F   1200912    /* 256 */
#define OFF_WK2F   1201168    /* 9216 */
#define OFF_WV2F   1210384    /* 9216 */
#define OFF_P      1219600    /* 400000 */
#define OFF_EXPV   1619600    /* 160000 (dst-sorted order) */
#define OFF_VBUF   1779600    /* 6400000 (dst-sorted order) */
#define OFF_DEG    8179600    /* 10000 ints (dst); reused as Z (zeroed at end of scan) */
#define OFF_Z      8179600    /* alias of OFF_DEG */
#define OFF_DEG2   8189600    /* 10000 ints (src) -- adjacent to DEG: single memset */
#define OFF_START  8199600    /* 10001 ints */
#define OFF_START2 8209601    /* 10001 ints */
#define OFF_CURS   8219602    /* 10000 ints */
#define OFF_CURS2  8229602    /* 10000 ints */
#define OFF_DPOS   8239602    /* 160000 ints: dst-position of edge at src-sorted slot (old ELIST slot) */
#define OFF_ELIST2 8399602    /* 160000 ints */
#define OFF_G      8559632    /* 30,720,000 bf16 = 15,360,000 float slots (16B aligned) */
/* total 23,919,632 floats = 95.7 MB (same extent as R5-R7 -- verified mapped) */

static __device__ __forceinline__ float bf2f(__hip_bfloat16 b) { return __bfloat162float(b); }
static __device__ __forceinline__ float sanitize(float v) {
    return fminf(fmaxf(v, -1e30f), 1e30f);
}
static __device__ __forceinline__ unsigned short f2bf(float f) {
    unsigned x = __float_as_uint(f);
    unsigned r = (x + 0x7fffu + ((x >> 16) & 1u)) >> 16;   /* RN-even */
    return (unsigned short)r;
}
static __device__ __forceinline__ float bflo(unsigned u) { return __uint_as_float(u << 16); }
static __device__ __forceinline__ float bfhi(unsigned u) { return __uint_as_float(u & 0xffff0000u); }

/* load 4 consecutive floats from a maybe-bf16 / maybe-f32 buffer at element index 4*i4 */
static __device__ __forceinline__ float4 load4(const void* p, int i4, int f32)
{
    if (f32) return ((const float4*)p)[i4];
    uint2 u = ((const uint2*)p)[i4];
    float4 r;
    r.x = bflo(u.x); r.y = bfhi(u.x);
    r.z = bflo(u.y); r.w = bfhi(u.y);
    return r;
}

// ---------------- prep: dtype detect + vectorized ingest + degree counts ----------------
__global__ __launch_bounds__(256) void prep_kernel(
    const void* __restrict__ x,   const void* __restrict__ ea,  const void* __restrict__ amf,
    const void* __restrict__ Wq0, const void* __restrict__ Wq1,
    const void* __restrict__ Wk1, const void* __restrict__ Wk2,
    const void* __restrict__ Wv1, const void* __restrict__ Wv2,
    const void* __restrict__ Wd0, const void* __restrict__ Wd1,
    const int* __restrict__ ei, float* __restrict__ ws)
{
    __shared__ int sflag;
    const int tid = threadIdx.x;
    if (tid == 0) {
        const unsigned short* xb = (const unsigned short*)x;
        int cnt = 0;
        for (int k = 0; k < 256; k += 2) {
            unsigned e = (unsigned)((xb[k] >> 7) & 0xFF);
            if (e >= 141) ++cnt;
        }
        sflag = (cnt >= 8) ? 1 : 0;                  /* 1 = inputs are fp32 */
        if (blockIdx.x == 0) *(int*)ws = sflag;
    }
    __syncthreads();
    const int f32 = sflag;
    const int i = blockIdx.x * 256 + tid;            /* 625 blocks -> 160000 threads */

    if (i < 100000) ((float4*)(ws + OFF_XF))[i] = load4(x, i, f32);
    if (i < 160000) ((float4*)(ws + OFF_EAF))[i] = load4(ea, i, f32);
    if (i < 40000)  ((float4*)(ws + OFF_AMFF))[i] = load4(amf, i, f32);
    if (i < 40000) {
#pragma unroll
        for (int k = 0; k < 4; ++k) {
            atomicAdd((int*)(ws + OFF_DEG)  + ei[E_CNT + 4 * i + k], 1);   /* dst degree */
            atomicAdd((int*)(ws + OFF_DEG2) + ei[4 * i + k], 1);           /* src degree */
        }
    }
    if (i < 2304) {
        ((float4*)(ws + OFF_WK2F))[i] = load4(Wk2, i, f32);
        ((float4*)(ws + OFF_WV2F))[i] = load4(Wv2, i, f32);
    }
    if (i < 64) {
        ((float4*)(ws + OFF_WQ0F))[i] = load4(Wq0, i, f32);
        ((float4*)(ws + OFF_WD0F))[i] = load4(Wd0, i, f32);
        ((float4*)(ws + OFF_WK1F))[i] = load4(Wk1, i, f32);
        ((float4*)(ws + OFF_WV1F))[i] = load4(Wv1, i, f32);
    }
    if (i < 16) {
        ((float4*)(ws + OFF_WQ1F))[i] = load4(Wq1, i, f32);
        ((float4*)(ws + OFF_WD1F))[i] = load4(Wd1, i, f32);
    }
}

// ---------------- dual scan (512 threads: half dst, half src) + zero Z at end ----------------
__global__ __launch_bounds__(512) void scan_kernel(float* __restrict__ ws)
{
    __shared__ int ssum[512];
    const int t    = threadIdx.x;
    const int half = t >> 8;
    const int lt   = t & 255;
    int* deg   = (int*)(ws + (half ? OFF_DEG2   : OFF_DEG));
    int* start = (int*)(ws + (half ? OFF_START2 : OFF_START));
    int* curs  = (int*)(ws + (half ? OFF_CURS2  : OFF_CURS));
    const int base = lt * 40;
    int s = 0;
    for (int k = 0; k < 40; ++k) {
        int idx = base + k;
        if (idx < N_CNT) s += deg[idx];
    }
    ssum[t] = s;
    __syncthreads();
    for (int off = 1; off < 256; off <<= 1) {
        int v = (lt >= off) ? ssum[t - off] : 0;
        __syncthreads();
        ssum[t] += v;
        __syncthreads();
    }
    int run = ssum[t] - s;
    for (int k = 0; k < 40; ++k) {
        int idx = base + k;
        if (idx < N_CNT) {
            start[idx] = run;
            curs[idx]  = run;
            run += deg[idx];
        }
    }
    if (lt == 255) start[N_CNT] = E_CNT;
    __syncthreads();                                   /* all deg reads done */
    for (int k = t; k < N_CNT; k += 512) ws[OFF_Z + k] = 0.f;   /* Z aliases DEG */
}

// ---------------- fused: blocks [0,625) fill, [625,1875) G, [1875,1915) P ----------------
// G row layout per (n,p,c): 96 bf16 = 48 u32 = 12 uint4:
// [0..15] G1[w], [16..23] G2[w], [24+w*3+i] G3[w][i] (w<8), [48+w*3+i] G4[w][i] (1/sqrt3 folded)
__global__ __launch_bounds__(256) void fillgp_kernel(const int* __restrict__ ei, float* __restrict__ ws)
{
    const int blk = blockIdx.x;
    const int tid = threadIdx.x;
    if (blk < 625) {
        /* ---- fill src-CSR + record dst-position per src-slot ---- */
        const int e = blk * 256 + tid;                 /* 625*256 = 160000 exact */
        int pd = atomicAdd((int*)(ws + OFF_CURS)  + ei[E_CNT + e], 1);
        int ps = atomicAdd((int*)(ws + OFF_CURS2) + ei[e], 1);
        ((int*)(ws + OFF_ELIST2))[ps] = e;
        ((int*)(ws + OFF_DPOS))[ps]   = pd;
        return;
    }
    if (blk >= 1875) {
        /* ---- P part ---- */
        const int n = (blk - 1875) * 256 + tid;
        if (n >= N_CNT) return;
        const float* WQ0 = ws + OFF_WQ0F;
        const float* WQ1 = ws + OFF_WQ1F;
        const float* WD0 = ws + OFF_WD0F;
        const float* WD1 = ws + OFF_WD1F;
        float xs[40];
        const float4* xr = (const float4*)(ws + OFF_XF + n * 40);
#pragma unroll
        for (int k = 0; k < 10; ++k) {
            float4 f = xr[k];
            xs[4 * k + 0] = f.x; xs[4 * k + 1] = f.y; xs[4 * k + 2] = f.z; xs[4 * k + 3] = f.w;
        }
        float q0[16];
#pragma unroll
        for (int w = 0; w < 16; ++w) {
            float s = 0.f;
#pragma unroll
            for (int u = 0; u < 16; ++u) s = fmaf(xs[u], WQ0[u * 16 + w], s);
            q0[w] = s * 0.25f;
        }
        float* pn = ws + OFF_P + n * 40;
#pragma unroll
        for (int v = 0; v < 16; ++v) {
            float s = 0.f;
#pragma unroll
            for (int w = 0; w < 16; ++w) s = fmaf(q0[w], WD0[w * 16 + v], s);
            pn[v] = sanitize(s * INVS320);
        }
        float q1[24];
#pragma unroll
        for (int w = 0; w < 8; ++w) {
            float s0 = 0.f, s1 = 0.f, s2 = 0.f;
#pragma unroll
            for (int u = 0; u < 8; ++u) {
                float wq = WQ1[u * 8 + w];
                s0 = fmaf(xs[16 + u * 3 + 0], wq, s0);
                s1 = fmaf(xs[16 + u * 3 + 1], wq, s1);
                s2 = fmaf(xs[16 + u * 3 + 2], wq, s2);
            }
            q1[w * 3 + 0] = s0 * INVS8;
            q1[w * 3 + 1] = s1 * INVS8;
            q1[w * 3 + 2] = s2 * INVS8;
        }
#pragma unroll
        for (int v = 0; v < 8; ++v) {
            float s0 = 0.f, s1 = 0.f, s2 = 0.f;
#pragma unroll
            for (int w = 0; w < 8; ++w) {
                float wd = WD1[w * 8 + v];
                s0 = fmaf(q1[w * 3 + 0], wd, s0);
                s1 = fmaf(q1[w * 3 + 1], wd, s1);
                s2 = fmaf(q1[w * 3 + 2], wd, s2);
            }
            const float sc = INVS320 * INV_SQRT3;
            pn[16 + v * 3 + 0] = sanitize(s0 * sc);
            pn[16 + v * 3 + 1] = sanitize(s1 * sc);
            pn[16 + v * 3 + 2] = sanitize(s2 * sc);
        }
        return;
    }
    /* ---- G part: thread = (pass, c, node) ---- */
    const int t = (blk - 625) * 256 + tid;             /* < 320000 */
    const int p   = t / 160000;
    const int rem = t - p * 160000;
    const int c   = rem / 10000;
    const int n   = rem - c * 10000;

    const float* W2 = ws + (p ? OFF_WV2F : OFF_WK2F) + c * 576;
    float x0[16], x1[24];
    {
        const float4* xr = (const float4*)(ws + OFF_XF + n * 40);
        float xs[40];
#pragma unroll
        for (int k = 0; k < 10; ++k) {
            float4 f = xr[k];
            xs[4 * k + 0] = f.x; xs[4 * k + 1] = f.y; xs[4 * k + 2] = f.z; xs[4 * k + 3] = f.w;
        }
#pragma unroll
        for (int u = 0; u < 16; ++u) x0[u] = xs[u];
#pragma unroll
        for (int u = 0; u < 24; ++u) x1[u] = xs[16 + u];
    }

    float out[96];
#pragma unroll
    for (int w = 0; w < 16; ++w) {
        float s = 0.f;
#pragma unroll
        for (int u = 0; u < 16; ++u) s = fmaf(W2[u * 16 + w], x0[u], s);
        out[w] = s;
    }
#pragma unroll
    for (int w = 0; w < 8; ++w) {
        float s = 0.f;
#pragma unroll
        for (int u = 0; u < 16; ++u) s = fmaf(W2[256 + u * 8 + w], x0[u], s);
        out[16 + w] = s;
    }
#pragma unroll
    for (int w = 0; w < 8; ++w) {
        float s0 = 0.f, s1 = 0.f, s2 = 0.f;
#pragma unroll
        for (int u = 0; u < 8; ++u) {
            float wv = W2[384 + u * 8 + w];
            s0 = fmaf(wv, x1[u * 3 + 0], s0);
            s1 = fmaf(wv, x1[u * 3 + 1], s1);
            s2 = fmaf(wv, x1[u * 3 + 2], s2);
        }
        out[24 + w * 3 + 0] = s0;
        out[24 + w * 3 + 1] = s1;
        out[24 + w * 3 + 2] = s2;
    }
#pragma unroll
    for (int w = 0; w < 16; ++w) {
        float s0 = 0.f, s1 = 0.f, s2 = 0.f;
#pragma unroll
        for (int u = 0; u < 8; ++u) {
            float wv = W2[448 + u * 16 + w];
            s0 = fmaf(wv, x1[u * 3 + 0], s0);
            s1 = fmaf(wv, x1[u * 3 + 1], s1);
            s2 = fmaf(wv, x1[u * 3 + 2], s2);
        }
        out[48 + w * 3 + 0] = s0 * INV_SQRT3;
        out[48 + w * 3 + 1] = s1 * INV_SQRT3;
        out[48 + w * 3 + 2] = s2 * INV_SQRT3;
    }

    uint4 ov[12];
    unsigned* ou = (unsigned*)ov;
#pragma unroll
    for (int k = 0; k < 48; ++k)
        ou[k] = (unsigned)f2bf(out[2 * k]) | ((unsigned)f2bf(out[2 * k + 1]) << 16);
    uint4* dp = (uint4*)((unsigned short*)(ws + OFF_G) + ((size_t)n * 2 + p) * 1536 + c * 96);
#pragma unroll
    for (int q = 0; q < 12; ++q) dp[q] = ov[q];
}

// ---------------- edge-kernel helpers ----------------
static __device__ __forceinline__ void load48(unsigned (&ub)[48], const uint4* __restrict__ rp)
{
#pragma unroll
    for (int q = 0; q < 12; ++q) {
        uint4 v = rp[q];
        ub[4 * q + 0] = v.x; ub[4 * q + 1] = v.y;
        ub[4 * q + 2] = v.z; ub[4 * q + 3] = v.w;
    }
}

static __device__ __forceinline__ void accum48(const unsigned (&ub)[48], float hc, float sh0,
    float s1x, float s1y, float s1z,
    float (&o0)[16], float (&o1)[24], float (&t2a)[8])
{
    const float hs = hc * sh0;
#define GVAL(k) (((k) & 1) ? bfhi(ub[(k) >> 1]) : bflo(ub[(k) >> 1]))
#pragma unroll
    for (int w = 0; w < 16; ++w) o0[w] = fmaf(hs, GVAL(w), o0[w]);
#pragma unroll
    for (int w = 0; w < 8; ++w) t2a[w] = fmaf(hc, GVAL(16 + w), t2a[w]);
#pragma unroll
    for (int w = 0; w < 8; ++w) {
        o1[w * 3 + 0] = fmaf(hs, GVAL(24 + w * 3 + 0), o1[w * 3 + 0]);
        o1[w * 3 + 1] = fmaf(hs, GVAL(24 + w * 3 + 1), o1[w * 3 + 1]);
        o1[w * 3 + 2] = fmaf(hs, GVAL(24 + w * 3 + 2), o1[w * 3 + 2]);
    }
#pragma unroll
    for (int w = 0; w < 16; ++w) {
        float g = GVAL(48 + w * 3 + 0) * s1x;
        g = fmaf(GVAL(48 + w * 3 + 1), s1y, g);
        g = fmaf(GVAL(48 + w * 3 + 2), s1z, g);
        o0[w] = fmaf(hc, g, o0[w]);
    }
#undef GVAL
}

// ---------------- per-edge main kernel: 2 threads/edge, ping-pong prefetch over c ----------------
__global__ __launch_bounds__(256, 2) void edge_kernel(
    const int* __restrict__ ei, float* __restrict__ ws)
{
    __shared__ float h_s[16 * 256];
    const int tid  = threadIdx.x;
    const int pass = tid >> 7;          /* waves 0-1: K, waves 2-3: V */
    const int lane = tid & 127;
    /* XCD swizzle: give each XCD a contiguous src range */
    const int b  = blockIdx.x;
    const int lb = (b < 1248) ? ((b & 7) * 156 + (b >> 3)) : b;
    const int sidx = lb * 128 + lane;   /* src-sorted edge index */
    const int e    = ((const int*)(ws + OFF_ELIST2))[sidx];
    const int dpos = ((const int*)(ws + OFF_DPOS))[sidx];
    const int src  = ei[e];
    const int dst  = ei[E_CNT + e];

    const float d   = ws[OFF_AMFF + e];
    const float dsv = d * INV_STEP;
    float emb[16];
#pragma unroll
    for (int bb = 0; bb < 16; ++bb) {
        float t1 = dsv - (float)bb;
        float t2 = (float)(bb + 2) - dsv;
        float v = 0.f;
        if (t1 > 0.f && t2 > 0.f) v = EMB_C * expf(-1.f / t1 - 1.f / t2);
        emb[bb] = v;
    }

    const float* W1 = ws + (pass ? OFF_WV1F : OFF_WK1F);
#pragma unroll 1
    for (int j = 0; j < 16; ++j) {
        float s = 0.f;
#pragma unroll
        for (int bb = 0; bb < 16; ++bb) s = fmaf(emb[bb], W1[bb * 16 + j], s);
        s *= 0.25f;
        h_s[j * 256 + tid] = s / (1.f + expf(-s));
    }

    const float4 eav = ((const float4*)(ws + OFF_EAF))[e];
    const float sh0 = eav.x, s1x = eav.y, s1y = eav.z, s1z = eav.w;

    float o0[16], o1[24], t2a[8];
#pragma unroll
    for (int i = 0; i < 16; ++i) o0[i] = 0.f;
#pragma unroll
    for (int i = 0; i < 24; ++i) o1[i] = 0.f;
#pragma unroll
    for (int i = 0; i < 8; ++i) t2a[i] = 0.f;

    const uint4* Gp = (const uint4*)((const unsigned short*)(ws + OFF_G)
                                     + ((size_t)src * 2 + pass) * 1536);

    unsigned A[48], B[48];
    load48(A, Gp);                                     /* c = 0 */
#pragma unroll 1
    for (int c = 0; c < 16; c += 2) {
        load48(B, Gp + (c + 1) * 12);                  /* prefetch c+1 */
        accum48(A, h_s[c * 256 + tid], sh0, s1x, s1y, s1z, o0, o1, t2a);
        if (c + 2 < 16) load48(A, Gp + (c + 2) * 12);  /* prefetch c+2 */
        accum48(B, h_s[(c + 1) * 256 + tid], sh0, s1x, s1y, s1z, o0, o1, t2a);
    }

#pragma unroll
    for (int w = 0; w < 8; ++w) {
        o1[w * 3 + 0] = fmaf(t2a[w], s1x, o1[w * 3 + 0]);
        o1[w * 3 + 1] = fmaf(t2a[w], s1y, o1[w * 3 + 1]);
        o1[w * 3 + 2] = fmaf(t2a[w], s1z, o1[w * 3 + 2]);
    }

    if (pass == 0) {
        const float* pd = ws + OFF_P + dst * 40;
        float sc = 0.f;
#pragma unroll
        for (int j = 0; j < 16; ++j) sc = fmaf(o0[j], pd[j], sc);
#pragma unroll
        for (int j = 0; j < 24; ++j) sc = fmaf(o1[j], pd[16 + j], sc);
        sc = fminf(fmaxf(sc * KSCALE, -60.f), 60.f);
        float ct = 10.f * (1.f - d * 0.125f);
        float cutoff = (ct > 0.f) ? expf(-1.f / ct) : 0.f;
        float ev = fmaxf(cutoff * expf(sc), 0.f);
        ws[OFF_EXPV + dpos] = ev;                      /* dst-sorted slot */
        atomicAdd(ws + OFF_Z + dst, ev);
    } else {
        float* vr = ws + OFF_VBUF + (size_t)dpos * 40; /* dst-sorted slot */
#pragma unroll
        for (int j = 0; j < 16; ++j) vr[j] = sanitize(o0[j] * KSCALE);
#pragma unroll
        for (int j = 0; j < 24; ++j) vr[16 + j] = sanitize(o1[j] * KSCALE);
    }
}

// ---------------- gather: one thread per (node, feature); fully streaming reads ----------------
__global__ __launch_bounds__(256) void gather_kernel(
    const float* __restrict__ ws, void* __restrict__ out)
{
    const int i = blockIdx.x * 256 + threadIdx.x;
    if (i >= N_CNT * 40) return;
    const int n = i / 40;
    const int f = i - n * 40;
    const int* start = (const int*)(ws + OFF_START);
    const float* expv = ws + OFF_EXPV;
    const float* Vbuf = ws + OFF_VBUF;
    const int s = start[n], t = start[n + 1];

    float zz = ws[OFF_Z + n];
    const float rz = (zz > 0.f) ? 1.f / zz : 1.f;

    float acc = 0.f;
    for (int j = s; j < t; ++j) {
        const float we = sqrtf(fmaxf(expv[j] * rz, 0.f));
        acc = fmaf(we, Vbuf[(size_t)j * 40 + f], acc);
    }
    acc = sanitize(acc);
    const int f32 = *(const int*)ws;
    if (f32) ((float*)out)[i] = acc;
    else     ((__hip_bfloat16*)out)[i] = __float2bfloat16(acc);
}

extern "C" void kernel_launch(void* const* d_in, const int* in_sizes, int n_in,
                              void* d_out, int out_size, void* d_ws, size_t ws_size,
                              hipStream_t stream)
{
    (void)in_sizes; (void)n_in; (void)out_size; (void)ws_size;
    const void* x   = d_in[0];
    const int*  ei  = (const int*)d_in[1];
    const void* ea  = d_in[2];
    const void* amf = d_in[5];
    const void* Wq0 = d_in[6];
    const void* Wq1 = d_in[7];
    const void* Wk1 = d_in[8];
    const void* Wk2 = d_in[9];
    const void* Wv1 = d_in[10];
    const void* Wv2 = d_in[11];
    const void* Wd0 = d_in[12];
    const void* Wd1 = d_in[13];

    float* ws = (float*)d_ws;

    hipMemsetAsync(ws + OFF_DEG, 0, 20000 * sizeof(int), stream);   /* DEG + DEG2 adjacent */
    prep_kernel<<<625, 256, 0, stream>>>(x, ea, amf, Wq0, Wq1, Wk1, Wk2, Wv1, Wv2, Wd0, Wd1, ei, ws);
    scan_kernel<<<1, 512, 0, stream>>>(ws);
    fillgp_kernel<<<1915, 256, 0, stream>>>(ei, ws);   /* 0-624 fill, 625-1874 G, 1875-1914 P */
    edge_kernel<<<1250, 256, 0, stream>>>(ei, ws);
    gather_kernel<<<(N_CNT * 40 + 255) / 256, 256, 0, stream>>>(ws, d_out);
}